// Round 6
// baseline (119.991 us; speedup 1.0000x reference)
//
#include <hip/hip_runtime.h>

// EMD / min-cost-assignment over 6 points, D=64, B=32768.
// cost(perm) = T - 2 * sum_n p_n . t_perm(n)  with T = sum|p|^2 + sum|t|^2
// min over 720 perms == T - 2 * max-assignment(dot matrix), solved by
// Held-Karp DP over 2^6 subsets, fully unrolled (static register indexing).
//
// R5: add nontemporal hints on the streaming P/T loads (no reuse -> no
// retention value in L1/L2/L3). Everything else identical to R3:
// 8 lanes/batch, 4 waves/SIMD, per-block partials to d_ws + 1-block reduce.
// dur_us decomposition: ~95us of the ~115us is harness poison/restore
// (41us 256MB ws fill + ~2x27us input restores); kernel is ~18-20us vs a
// 16us BW floor -> this is the last plausible controllable gain.

#define BLOCK 256

typedef float f4 __attribute__((ext_vector_type(4)));

__device__ __forceinline__ f4 ntload(const float* p) {
    return __builtin_nontemporal_load((const f4*)p);
}

__device__ __forceinline__ float dot4(f4 a, f4 b) {
    return a.x * b.x + a.y * b.y + a.z * b.z + a.w * b.w;
}

// compile-time popcount for 6-bit subsets (folds after full unroll)
#define PC6(S) (((S)&1) + (((S)>>1)&1) + (((S)>>2)&1) + (((S)>>3)&1) + (((S)>>4)&1) + (((S)>>5)&1))

__global__ __launch_bounds__(BLOCK, 4)
void emd_kernel(const float* __restrict__ preds,
                const float* __restrict__ targets,
                float* __restrict__ partials) {
    const int t    = blockIdx.x * BLOCK + threadIdx.x;
    const int b    = t >> 3;      // batch (grid is exact: B*8 threads)
    const int h    = t & 7;       // 8-lane split of the D=64 dims
    const int lane = threadIdx.x & 63;

    // lane h owns float4 slots {h, h+8} of each 16-float4 row: the h-th 16B
    // of each 128B half -> every load instr covers 128B contiguous per group.
    const float* P = preds   + (size_t)b * 384 + h * 4;
    const float* T = targets + (size_t)b * 384 + h * 4;

    float d[6][6];
#pragma unroll
    for (int n = 0; n < 6; ++n)
#pragma unroll
        for (int m = 0; m < 6; ++m) d[n][m] = 0.0f;
    float tn = 0.0f;  // partial |p|^2 + |t|^2 over this lane's dims

#pragma unroll
    for (int c = 0; c < 2; ++c) {      // 128B half of each 256B row
        f4 pv[6], tv[6];
#pragma unroll
        for (int n = 0; n < 6; ++n)
            pv[n] = ntload(P + n * 64 + c * 32);
#pragma unroll
        for (int m = 0; m < 6; ++m)
            tv[m] = ntload(T + m * 64 + c * 32);
#pragma unroll
        for (int n = 0; n < 6; ++n) {
            tn += dot4(pv[n], pv[n]) + dot4(tv[n], tv[n]);
#pragma unroll
            for (int m = 0; m < 6; ++m)
                d[n][m] += dot4(pv[n], tv[m]);
        }
    }

    // combine the 8 per-lane partials (lanes differ only in low 3 bits)
#pragma unroll
    for (int o = 1; o <= 4; o <<= 1) {
#pragma unroll
        for (int n = 0; n < 6; ++n)
#pragma unroll
            for (int m = 0; m < 6; ++m)
                d[n][m] += __shfl_xor(d[n][m], o);
        tn += __shfl_xor(tn, o);
    }

    // Held-Karp: g[S] = max assignment of preds 0..|S|-1 to target set S.
    // Fully unrolled: every index is compile-time constant -> registers.
    float g[64];
    g[0] = 0.0f;
#pragma unroll
    for (int S = 1; S < 64; ++S) {
        float bst = -3.4e38f;
#pragma unroll
        for (int m = 0; m < 6; ++m) {
            if (S & (1 << m)) {
                float cand = g[S ^ (1 << m)] + d[PC6(S) - 1][m];
                bst = fmaxf(bst, cand);
            }
        }
        g[S] = bst;
    }
    const float best = tn - 2.0f * g[63];   // min over all 720 permutations

    // block reduction: one lane per 8-group contributes
    float v = (h == 0) ? best : 0.0f;
#pragma unroll
    for (int o = 8; o < 64; o <<= 1) v += __shfl_xor(v, o);

    __shared__ float wsum[BLOCK / 64];
    const int wid = threadIdx.x >> 6;
    if (lane == 0) wsum[wid] = v;
    __syncthreads();
    if (threadIdx.x == 0) {
        float s = 0.0f;
#pragma unroll
        for (int i = 0; i < BLOCK / 64; ++i) s += wsum[i];
        partials[blockIdx.x] = s;   // plain store, no atomic
    }
}

__global__ __launch_bounds__(256)
void reduce_kernel(const float* __restrict__ partials,
                   float* __restrict__ out, int n) {
    float v = 0.0f;
    for (int i = threadIdx.x; i < n; i += 256) v += partials[i];
#pragma unroll
    for (int o = 1; o < 64; o <<= 1) v += __shfl_xor(v, o);
    __shared__ float s[4];
    if ((threadIdx.x & 63) == 0) s[threadIdx.x >> 6] = v;
    __syncthreads();
    if (threadIdx.x == 0) out[0] = s[0] + s[1] + s[2] + s[3];
}

extern "C" void kernel_launch(void* const* d_in, const int* in_sizes, int n_in,
                              void* d_out, int out_size, void* d_ws, size_t ws_size,
                              hipStream_t stream) {
    const float* preds   = (const float*)d_in[0];
    const float* targets = (const float*)d_in[1];
    float* out = (float*)d_out;
    float* partials = (float*)d_ws;
    const int B = in_sizes[0] / 384;   // 6 * 64 floats per batch

    const int total = B * 8;           // 8 lanes per batch
    const int grid  = (total + BLOCK - 1) / BLOCK;
    emd_kernel<<<grid, BLOCK, 0, stream>>>(preds, targets, partials);
    reduce_kernel<<<1, 256, 0, stream>>>(partials, out, grid);
}

// Round 8
// 116.125 us; speedup vs baseline: 1.0333x; 1.0333x over previous
//
#include <hip/hip_runtime.h>

// EMD / min-cost-assignment over 6 points, D=64, B=32768.
// cost(perm) = T - 2 * sum_n p_n . t_perm(n)  with T = sum|p|^2 + sum|t|^2
// min over 720 perms == T - 2 * max-assignment(dot matrix), solved by
// Held-Karp DP over 2^6 subsets, fully unrolled (static register indexing).
//
// R7 (resubmit of R6 revert; R7 bench hit infra failure): byte-identical to
// the best measured kernel (R3, 115.4 us). R5's nontemporal-load experiment
// regressed (115.4 -> 120.0 us: harness input-restore leaves the 100MB of
// inputs L3-resident; nt hints forfeit that retention). Structure:
// 8 lanes/batch (4 waves/SIMD, 128B-contiguous group loads), shfl-combined
// partial dot matrices, fully unrolled Held-Karp DP, per-block partials to
// d_ws + 1-block final reduce. ~95us of dur_us is fixed harness
// poison/restore; kernel ~18-20us vs a ~16us BW floor.

#define BLOCK 256

__device__ __forceinline__ float dot4(float4 a, float4 b) {
    return a.x * b.x + a.y * b.y + a.z * b.z + a.w * b.w;
}

// compile-time popcount for 6-bit subsets (folds after full unroll)
#define PC6(S) (((S)&1) + (((S)>>1)&1) + (((S)>>2)&1) + (((S)>>3)&1) + (((S)>>4)&1) + (((S)>>5)&1))

__global__ __launch_bounds__(BLOCK, 4)
void emd_kernel(const float* __restrict__ preds,
                const float* __restrict__ targets,
                float* __restrict__ partials) {
    const int t    = blockIdx.x * BLOCK + threadIdx.x;
    const int b    = t >> 3;      // batch (grid is exact: B*8 threads)
    const int h    = t & 7;       // 8-lane split of the D=64 dims
    const int lane = threadIdx.x & 63;

    // lane h owns float4 slots {h, h+8} of each 16-float4 row: the h-th 16B
    // of each 128B half -> every load instr covers 128B contiguous per group.
    const float* P = preds   + (size_t)b * 384 + h * 4;
    const float* T = targets + (size_t)b * 384 + h * 4;

    float d[6][6];
#pragma unroll
    for (int n = 0; n < 6; ++n)
#pragma unroll
        for (int m = 0; m < 6; ++m) d[n][m] = 0.0f;
    float tn = 0.0f;  // partial |p|^2 + |t|^2 over this lane's dims

#pragma unroll
    for (int c = 0; c < 2; ++c) {      // 128B half of each 256B row
        float4 pv[6], tv[6];
#pragma unroll
        for (int n = 0; n < 6; ++n)
            pv[n] = *(const float4*)(P + n * 64 + c * 32);
#pragma unroll
        for (int m = 0; m < 6; ++m)
            tv[m] = *(const float4*)(T + m * 64 + c * 32);
#pragma unroll
        for (int n = 0; n < 6; ++n) {
            tn += dot4(pv[n], pv[n]) + dot4(tv[n], tv[n]);
#pragma unroll
            for (int m = 0; m < 6; ++m)
                d[n][m] += dot4(pv[n], tv[m]);
        }
    }

    // combine the 8 per-lane partials (lanes differ only in low 3 bits)
#pragma unroll
    for (int o = 1; o <= 4; o <<= 1) {
#pragma unroll
        for (int n = 0; n < 6; ++n)
#pragma unroll
            for (int m = 0; m < 6; ++m)
                d[n][m] += __shfl_xor(d[n][m], o);
        tn += __shfl_xor(tn, o);
    }

    // Held-Karp: g[S] = max assignment of preds 0..|S|-1 to target set S.
    // Fully unrolled: every index is compile-time constant -> registers.
    float g[64];
    g[0] = 0.0f;
#pragma unroll
    for (int S = 1; S < 64; ++S) {
        float bst = -3.4e38f;
#pragma unroll
        for (int m = 0; m < 6; ++m) {
            if (S & (1 << m)) {
                float cand = g[S ^ (1 << m)] + d[PC6(S) - 1][m];
                bst = fmaxf(bst, cand);
            }
        }
        g[S] = bst;
    }
    const float best = tn - 2.0f * g[63];   // min over all 720 permutations

    // block reduction: one lane per 8-group contributes
    float v = (h == 0) ? best : 0.0f;
#pragma unroll
    for (int o = 8; o < 64; o <<= 1) v += __shfl_xor(v, o);

    __shared__ float wsum[BLOCK / 64];
    const int wid = threadIdx.x >> 6;
    if (lane == 0) wsum[wid] = v;
    __syncthreads();
    if (threadIdx.x == 0) {
        float s = 0.0f;
#pragma unroll
        for (int i = 0; i < BLOCK / 64; ++i) s += wsum[i];
        partials[blockIdx.x] = s;   // plain store, no atomic
    }
}

__global__ __launch_bounds__(256)
void reduce_kernel(const float* __restrict__ partials,
                   float* __restrict__ out, int n) {
    float v = 0.0f;
    for (int i = threadIdx.x; i < n; i += 256) v += partials[i];
#pragma unroll
    for (int o = 1; o < 64; o <<= 1) v += __shfl_xor(v, o);
    __shared__ float s[4];
    if ((threadIdx.x & 63) == 0) s[threadIdx.x >> 6] = v;
    __syncthreads();
    if (threadIdx.x == 0) out[0] = s[0] + s[1] + s[2] + s[3];
}

extern "C" void kernel_launch(void* const* d_in, const int* in_sizes, int n_in,
                              void* d_out, int out_size, void* d_ws, size_t ws_size,
                              hipStream_t stream) {
    const float* preds   = (const float*)d_in[0];
    const float* targets = (const float*)d_in[1];
    float* out = (float*)d_out;
    float* partials = (float*)d_ws;
    const int B = in_sizes[0] / 384;   // 6 * 64 floats per batch

    const int total = B * 8;           // 8 lanes per batch
    const int grid  = (total + BLOCK - 1) / BLOCK;
    emd_kernel<<<grid, BLOCK, 0, stream>>>(preds, targets, partials);
    reduce_kernel<<<1, 256, 0, stream>>>(partials, out, grid);
}